// Round 6
// baseline (98.158 us; speedup 1.0000x reference)
//
#include <hip/hip_runtime.h>
#include <math.h>

#define LOG2E  1.44269504088896340736f
#define LN2    0.69314718055994530942f
#define LOG2PI 1.8378770664093453f

#define NN 2048
#define DD 64

__device__ __forceinline__ float fexp2(float x) { return __builtin_amdgcn_exp2f(x); }
__device__ __forceinline__ float flog2(float x) { return __builtin_amdgcn_logf(x); }

__device__ __forceinline__ float2 fma2(float2 a, float2 b, float2 c) {
    return make_float2(fmaf(a.x, b.x, c.x), fmaf(a.y, b.y, c.y));
}
__device__ __forceinline__ float2 bcast2(float v) { return make_float2(v, v); }

// Software exp2 on the main VALU pipe (6 insts, no trans):
// n = rndne(x); f = x-n in [-0.5,0.5]; deg-2 poly; ldexp.
// Rel err <= ~0.9% -> harmless at tolerance 9.8.
__device__ __forceinline__ float2 swexp2x2(float2 x) {
    const float C2 = 0.2402265069591007f, C1 = 0.6931471805599453f;
    float nfx = __builtin_rintf(x.x), nfy = __builtin_rintf(x.y);
    int   nx  = (int)nfx,             ny  = (int)nfy;
    float fx  = x.x - nfx,            fy  = x.y - nfy;
    float px  = fmaf(fmaf(C2, fx, C1), fx, 1.0f);
    float py  = fmaf(fmaf(C2, fy, C1), fy, 1.0f);
    return make_float2(__builtin_amdgcn_ldexpf(px, nx),
                       __builtin_amdgcn_ldexpf(py, ny));
}

// ---------------------------------------------------------------------------
// K1: per-(j,d) factors. a*log2e = z2*p + z*q + r2 with
//   p = -0.5*exp(-lv)*log2e, q = -2*mean*p, r2 = mean^2*p -0.5*(lv+LOG2PI)*log2e
// Outputs: packed[j][d]={p,q,r2,0}; pqT[d][j]={p,q}; zz[i][d]={z^2,z}; r[j]=sum_d r2
// ---------------------------------------------------------------------------
__global__ __launch_bounds__(1024) void k1_precompute(
    const float* __restrict__ z, const float* __restrict__ z_mean,
    const float* __restrict__ z_lv,
    float4* __restrict__ packed, float2* __restrict__ pqT,
    float2* __restrict__ zz, float* __restrict__ r)
{
    __shared__ float aL[64][65], bL[64][65], cL[64][65];
    int tid  = threadIdx.x;
    int lane = tid & 63;     // d in compute phases, j in store phases
    int row  = tid >> 6;     // 0..15
    int jb   = blockIdx.x * 64;

    #pragma unroll
    for (int ppp = 0; ppp < 4; ++ppp) {
        int jl  = ppp * 16 + row;
        int idx = (jb + jl) * DD + lane;
        float mean = z_mean[idx], lv = z_lv[idx];
        float p   = -0.5f * fexp2(-lv * LOG2E) * LOG2E;
        float q   = -2.0f * mean * p;
        float c22 = -0.5f * (lv + LOG2PI) * LOG2E;
        float r2  = fmaf(mean * mean, p, c22);
        packed[idx] = make_float4(p, q, r2, 0.0f);
        aL[jl][lane] = p; bL[jl][lane] = q; cL[jl][lane] = r2;
        // zz: direct coalesced store, i-major (same index space as j)
        float zv = z[idx];
        zz[idx] = make_float2(zv * zv, zv);
    }
    __syncthreads();
    #pragma unroll
    for (int ppp = 0; ppp < 4; ++ppp) {
        int dd = ppp * 16 + row;
        pqT[(size_t)dd * NN + jb + lane] = make_float2(aL[lane][dd], bL[lane][dd]);
    }
    if (tid < 64) {
        float s = 0.0f;
        #pragma unroll
        for (int dd = 0; dd < 64; ++dd) s += cL[tid][dd];
        r[jb + tid] = s;
    }
}

// ---------------------------------------------------------------------------
// K3: sums[jq][i][d] = sum_{j in quarter} 2^{z2*p + z*q + r2}  (fixed max 0).
// 12/16 elements use SW exp2 (VALU pipe), 4/16 the HW trans pipe.
// Block: 1024 thr = 16 waves; i-tile 16; wave owns 32 j's; lane = d.
// Grid: 128 i-tiles x 4 j-quarters = 512 blocks (2 blocks/CU, 8 waves/SIMD).
// ---------------------------------------------------------------------------
__global__ __launch_bounds__(1024) void k3_perd(
    const float* __restrict__ z, const float4* __restrict__ packed,
    float* __restrict__ sums)
{
    __shared__ float sm[16][16][DD];   // 64 KB
    int lane = threadIdx.x & 63;
    int w    = threadIdx.x >> 6;       // 0..15
    int tile = blockIdx.x >> 2;
    int jq   = blockIdx.x & 3;
    int i0   = tile * 16;

    float2 zp[8], z2p[8], s[8];
    #pragma unroll
    for (int k = 0; k < 8; ++k) {
        float za = z[(i0 + 2 * k)     * DD + lane];
        float zb = z[(i0 + 2 * k + 1) * DD + lane];
        zp[k]  = make_float2(za, zb);
        z2p[k] = make_float2(za * za, zb * zb);
        s[k]   = make_float2(0.0f, 0.0f);
    }

    const float4* pk_ = packed + ((size_t)(jq * 512 + w * 32)) * DD + lane;
    #pragma unroll 2
    for (int jj = 0; jj < 32; ++jj) {
        float4 c = pk_[(size_t)jj * DD];   // {p, q, r2, -}
        float2 cp = bcast2(c.x), cq = bcast2(c.y), cr = bcast2(c.z);
        #pragma unroll
        for (int k = 0; k < 6; ++k) {      // SW-exp pairs
            float2 arg = fma2(z2p[k], cp, fma2(zp[k], cq, cr));
            float2 e   = swexp2x2(arg);
            s[k].x += e.x; s[k].y += e.y;
        }
        #pragma unroll
        for (int k = 6; k < 8; ++k) {      // HW-exp pairs
            float2 arg = fma2(z2p[k], cp, fma2(zp[k], cq, cr));
            s[k].x += fexp2(arg.x); s[k].y += fexp2(arg.y);
        }
    }

    #pragma unroll
    for (int k = 0; k < 8; ++k) {
        sm[2 * k][w][lane]     = s[k].x;
        sm[2 * k + 1][w][lane] = s[k].y;
    }
    __syncthreads();

    // wave w finishes row i0+w
    float tot = 0.0f;
    #pragma unroll
    for (int w2 = 0; w2 < 16; ++w2) tot += sm[w][w2][lane];
    sums[((size_t)jq * NN + i0 + w) * DD + lane] = tot;
}

// ---------------------------------------------------------------------------
// K2: b2[i,j] = sum_d z2*p + z*q (+ r[j]); LDS-staged zz tile (8i x 64d),
// j = thread (coalesced pq loads), pk_fma accumulate, wave-merge LSE.
// Grid: 256 i-tiles x 4 j-blocks = 1024 blocks x 512 thr.
// ---------------------------------------------------------------------------
__global__ __launch_bounds__(512) void k2_logqz(
    const float2* __restrict__ zz, const float2* __restrict__ pqT,
    const float* __restrict__ r, float2* __restrict__ k2ms)
{
    __shared__ float2 zzL[DD][9];   // padded
    __shared__ float  pb[8][512];   // 16 KB
    int tid = threadIdx.x;
    int it  = blockIdx.x >> 2;
    int jb  = blockIdx.x & 3;
    int i0  = it * 8;
    int j   = jb * 512 + tid;

    {   // stage zz tile: 8 i x 64 d
        int i = tid >> 6, d = tid & 63;
        zzL[d][i] = zz[(size_t)(i0 + i) * DD + d];
    }
    __syncthreads();

    float2 acc[8];
    #pragma unroll
    for (int i = 0; i < 8; ++i) acc[i] = make_float2(0.0f, 0.0f);

    #pragma unroll 4
    for (int d = 0; d < DD; ++d) {
        float2 pq = pqT[(size_t)d * NN + j];   // coalesced
        #pragma unroll
        for (int i = 0; i < 8; ++i)
            acc[i] = fma2(zzL[d][i], pq, acc[i]);  // broadcast ds_read
    }

    float rj = r[j];
    #pragma unroll
    for (int i = 0; i < 8; ++i) pb[i][tid] = acc[i].x + acc[i].y + rj;
    __syncthreads();

    // wave w reduces row i0+w over 512 j's
    int w = tid >> 6, lane = tid & 63;
    float mm = -1e30f, ss = 0.0f;
    #pragma unroll
    for (int c = 0; c < 8; ++c) {
        float v  = pb[w][lane + 64 * c];
        float mn = fmaxf(mm, v);
        ss = ss * fexp2(mm - mn) + fexp2(v - mn);
        mm = mn;
    }
    #pragma unroll
    for (int off = 32; off; off >>= 1) {
        float m2 = __shfl_xor(mm, off, 64);
        float s2 = __shfl_xor(ss, off, 64);
        float mn = fmaxf(mm, m2);
        ss = ss * fexp2(mm - mn) + s2 * fexp2(m2 - mn);
        mm = mn;
    }
    if (lane == 0) k2ms[(size_t)jb * NN + i0 + w] = make_float2(mm, ss);
}

// ---------------------------------------------------------------------------
// K5: per i: lqp = ln2*sum_d log2(sum_q sums[q][i][d]); lq = ln2*LSE-merge of
// 4 (m,s) partials; diff = lqp - lq.  Block 256 thr = 4 i's; grid 512.
// ---------------------------------------------------------------------------
__global__ __launch_bounds__(256) void k5_merge(
    const float* __restrict__ sums, const float2* __restrict__ k2ms,
    float* __restrict__ diff)
{
    int lane = threadIdx.x & 63, w = threadIdx.x >> 6;
    int i = blockIdx.x * 4 + w;

    float tot = 0.0f;
    #pragma unroll
    for (int q = 0; q < 4; ++q) tot += sums[((size_t)q * NN + i) * DD + lane];
    float t = flog2(tot);
    #pragma unroll
    for (int off = 32; off; off >>= 1) t += __shfl_xor(t, off, 64);

    if (lane == 0) {
        float mm = -1e30f, ss = 0.0f;
        #pragma unroll
        for (int q = 0; q < 4; ++q) {
            float2 p = k2ms[(size_t)q * NN + i];
            float mn = fmaxf(mm, p.x);
            ss = ss * fexp2(mm - mn) + p.y * fexp2(p.x - mn);
            mm = mn;
        }
        diff[i] = LN2 * t - LN2 * (mm + flog2(ss));
    }
}

// ---------------------------------------------------------------------------
// K6: out = mean_i diff[i]
// ---------------------------------------------------------------------------
__global__ __launch_bounds__(256) void k6_final(
    const float* __restrict__ diff, float* __restrict__ out)
{
    __shared__ float red[256];
    int tid = threadIdx.x;
    float t = 0.0f;
    for (int k = tid; k < NN; k += 256) t += diff[k];
    red[tid] = t;
    __syncthreads();
    #pragma unroll
    for (int off = 128; off; off >>= 1) {
        if (tid < off) red[tid] += red[tid + off];
        __syncthreads();
    }
    if (tid == 0) out[0] = red[0] * (1.0f / (float)NN);
}

extern "C" void kernel_launch(void* const* d_in, const int* in_sizes, int n_in,
                              void* d_out, int out_size, void* d_ws, size_t ws_size,
                              hipStream_t stream)
{
    const float* z      = (const float*)d_in[0];
    const float* z_mean = (const float*)d_in[1];
    const float* z_lv   = (const float*)d_in[2];
    float* out = (float*)d_out;

    float* ws = (float*)d_ws;
    float4* packed = (float4*)ws;                       // N*D f4   (2 MB)
    float*  base   = ws + (size_t)NN * DD * 4;
    float2* pqT    = (float2*)base;                     // N*D f2   (1 MB)
    float2* zz     = (float2*)(base + (size_t)NN * DD * 2);  // N*D f2 (1 MB)
    float*  r      = base + (size_t)NN * DD * 4;        // N
    float*  sums   = r + NN;                            // 4*N*D    (2 MB)
    float*  k2ms_f = sums + (size_t)4 * NN * DD;        // 4*N f2
    float2* k2ms   = (float2*)k2ms_f;
    float*  diff   = k2ms_f + (size_t)8 * NN;           // N

    k1_precompute<<<NN / 64, 1024, 0, stream>>>(z, z_mean, z_lv, packed, pqT, zz, r);
    k3_perd<<<512, 1024, 0, stream>>>(z, packed, sums);
    k2_logqz<<<1024, 512, 0, stream>>>(zz, pqT, r, k2ms);
    k5_merge<<<NN / 4, 256, 0, stream>>>(sums, k2ms, diff);
    k6_final<<<1, 256, 0, stream>>>(diff, out);
}

// Round 7
// 78.260 us; speedup vs baseline: 1.2542x; 1.2542x over previous
//
#include <hip/hip_runtime.h>
#include <math.h>
#include <stdint.h>

#define LOG2E  1.44269504088896340736f
#define LN2    0.69314718055994530942f
#define LOG2PI 1.8378770664093453f

#define NN 2048
#define DD 64

// single-instruction transcendentals (v_exp_f32 / v_log_f32)
__device__ __forceinline__ float fexp2(float x) { return __builtin_amdgcn_exp2f(x); }
__device__ __forceinline__ float flog2(float x) { return __builtin_amdgcn_logf(x); }

// ---------------------------------------------------------------------------
// K1: per-(j,d) factors. a*log2e = z2*p + z*q + r2 with
//   p = -0.5*exp(-lv)*log2e, q = -2*mean*p, r2 = mean^2*p -0.5*(lv+LOG2PI)*log2e
// Outputs: packed[j][d]={p,q,r2,0}; pqT[d][j]={p,q}; zz[i][d]={z^2,z}; r[j]=sum_d r2
// ---------------------------------------------------------------------------
__global__ __launch_bounds__(1024) void k1_precompute(
    const float* __restrict__ z, const float* __restrict__ z_mean,
    const float* __restrict__ z_lv,
    float4* __restrict__ packed, float2* __restrict__ pqT,
    float2* __restrict__ zz, float* __restrict__ r)
{
    __shared__ float aL[64][65], bL[64][65], cL[64][65];
    int tid  = threadIdx.x;
    int lane = tid & 63;     // d in compute phases, j in store phases
    int row  = tid >> 6;     // 0..15
    int jb   = blockIdx.x * 64;

    #pragma unroll
    for (int ppp = 0; ppp < 4; ++ppp) {
        int jl  = ppp * 16 + row;
        int idx = (jb + jl) * DD + lane;
        float mean = z_mean[idx], lv = z_lv[idx];
        float p   = -0.5f * fexp2(-lv * LOG2E) * LOG2E;
        float q   = -2.0f * mean * p;
        float c22 = -0.5f * (lv + LOG2PI) * LOG2E;
        float r2  = fmaf(mean * mean, p, c22);
        packed[idx] = make_float4(p, q, r2, 0.0f);
        aL[jl][lane] = p; bL[jl][lane] = q; cL[jl][lane] = r2;
        float zv = z[idx];
        zz[idx] = make_float2(zv * zv, zv);
    }
    __syncthreads();
    #pragma unroll
    for (int ppp = 0; ppp < 4; ++ppp) {
        int dd = ppp * 16 + row;
        pqT[(size_t)dd * NN + jb + lane] = make_float2(aL[lane][dd], bL[lane][dd]);
    }
    if (tid < 64) {
        float s = 0.0f;
        #pragma unroll
        for (int dd = 0; dd < 64; ++dd) s += cL[tid][dd];
        r[jb + tid] = s;
    }
}

// ---------------------------------------------------------------------------
// K3: sums[jsl][i][d] = sum_{j in 128-slice} 2^{z2*p + z*q + r2}  (fixed max).
// LDS-tiled: 128-j slice staged in 4 chunks of 32 j x 64 d float4 (32 KB),
// double-buffered (64 KB). Stage loads issued BEFORE compute (latency hides
// under 32jj x 8i of math); ds_read_b128 inner loop.
// Block: 512 thr = 8 waves; wave owns 8 i's exclusively (no cross-wave
// reduce). Grid: 32 i-tiles x 16 j-slices = 512 blocks (2/CU by LDS).
// ---------------------------------------------------------------------------
__global__ __launch_bounds__(512) void k3_perd(
    const float* __restrict__ z, const float4* __restrict__ packed,
    float* __restrict__ sums)
{
    __shared__ float4 buf[2][32][DD];   // 64 KB
    int tid   = threadIdx.x;
    int lane  = tid & 63, w = tid >> 6;   // 8 waves
    int itile = blockIdx.x >> 4;
    int jsl   = blockIdx.x & 15;
    int i0    = itile * 64 + w * 8;
    int j0    = jsl * 128;

    float zr[8], z2r[8], s[8];
    #pragma unroll
    for (int k = 0; k < 8; ++k) {
        zr[k]  = z[(i0 + k) * DD + lane];
        z2r[k] = zr[k] * zr[k];
        s[k]   = 0.0f;
    }

    {   // stage chunk 0
        const float4* src = packed + (size_t)j0 * DD;
        float4* dst = &buf[0][0][0];
        #pragma unroll
        for (int r2 = 0; r2 < 4; ++r2) dst[tid + r2 * 512] = src[tid + r2 * 512];
    }
    __syncthreads();

    for (int c = 0; c < 4; ++c) {
        float4 stg[4];
        if (c < 3) {   // issue next chunk's loads early (fly under compute)
            const float4* src = packed + (size_t)(j0 + (c + 1) * 32) * DD;
            #pragma unroll
            for (int r2 = 0; r2 < 4; ++r2) stg[r2] = src[tid + r2 * 512];
        }
        const float4* bp = &buf[c & 1][0][lane];
        #pragma unroll 2
        for (int jj = 0; jj < 32; ++jj) {
            float4 t = bp[(size_t)jj * DD];   // {p, q, r2, -}
            #pragma unroll
            for (int k = 0; k < 8; ++k) {
                float arg = fmaf(z2r[k], t.x, fmaf(zr[k], t.y, t.z));
                s[k] += fexp2(arg);
            }
        }
        if (c < 3) {   // write-late into the other buffer
            float4* dst = &buf[(c + 1) & 1][0][0];
            #pragma unroll
            for (int r2 = 0; r2 < 4; ++r2) dst[tid + r2 * 512] = stg[r2];
        }
        __syncthreads();
    }

    #pragma unroll
    for (int k = 0; k < 8; ++k)
        sums[((size_t)jsl * NN + i0 + k) * DD + lane] = s[k];
}

// ---------------------------------------------------------------------------
// K2: acc[i] = sum_d z2*p + z*q; fixed-max partial sum (no online LSE):
//   part = sum_j 2^{acc + r[j] + 64}   (+64 shift keeps terms >> fp32
//   denormal floor: row max ~ -85 log2 -> -21; negligible terms underflow
//   harmlessly). zz tile (16i x 64d) in LDS, broadcast float4 reads;
//   pq coalesced float2. Grid: 128 i-tiles x 4 j-blocks = 512 x 512 thr.
// ---------------------------------------------------------------------------
__global__ __launch_bounds__(512) void k2_logqz(
    const float2* __restrict__ zz, const float2* __restrict__ pqT,
    const float* __restrict__ r, float* __restrict__ k2part)
{
    __shared__ float2 zzL[DD][16];   // 8 KB
    __shared__ float  pb[16][512];   // 32 KB
    int tid = threadIdx.x;
    int it  = blockIdx.x >> 2;
    int jb  = blockIdx.x & 3;
    int i0  = it * 16;
    int j   = jb * 512 + tid;

    #pragma unroll
    for (int t2 = 0; t2 < 2; ++t2) {
        int idx = t2 * 512 + tid;        // 16 i x 64 d
        int i = idx >> 6, d = idx & 63;
        zzL[d][i] = zz[(size_t)(i0 + i) * DD + d];
    }
    __syncthreads();

    float acc[16];
    #pragma unroll
    for (int i = 0; i < 16; ++i) acc[i] = 0.0f;

    #pragma unroll 2
    for (int d = 0; d < DD; ++d) {
        float2 pq = pqT[(size_t)d * NN + j];   // coalesced
        #pragma unroll
        for (int ip = 0; ip < 8; ++ip) {
            float4 t = *(const float4*)&zzL[d][2 * ip];   // broadcast
            acc[2 * ip]     = fmaf(t.x, pq.x, fmaf(t.y, pq.y, acc[2 * ip]));
            acc[2 * ip + 1] = fmaf(t.z, pq.x, fmaf(t.w, pq.y, acc[2 * ip + 1]));
        }
    }

    float rj = r[j] + 64.0f;   // +64 log2: underflow guard
    #pragma unroll
    for (int i = 0; i < 16; ++i) pb[i][tid] = fexp2(acc[i] + rj);
    __syncthreads();

    int w = tid >> 6, lane = tid & 63;
    #pragma unroll
    for (int half = 0; half < 2; ++half) {
        int i = w + half * 8;
        float ss = 0.0f;
        #pragma unroll
        for (int c = 0; c < 8; ++c) ss += pb[i][lane + 64 * c];
        #pragma unroll
        for (int off = 32; off; off >>= 1) ss += __shfl_xor(ss, off, 64);
        if (lane == 0) k2part[(size_t)jb * NN + i0 + i] = ss;
    }
}

// ---------------------------------------------------------------------------
// K5: diff[i] = ln2 * sum_d log2(sum_{16 jsl} sums) - ln2*(log2(sum_jb part)-64)
// Block 256 = 4 i's (wave per i, lane = d). Grid 512.
// ---------------------------------------------------------------------------
__global__ __launch_bounds__(256) void k5_merge(
    const float* __restrict__ sums, const float* __restrict__ k2part,
    float* __restrict__ diff)
{
    int lane = threadIdx.x & 63, w = threadIdx.x >> 6;
    int i = blockIdx.x * 4 + w;

    float tot = 0.0f;
    #pragma unroll
    for (int q = 0; q < 16; ++q) tot += sums[((size_t)q * NN + i) * DD + lane];
    float t = flog2(tot);
    #pragma unroll
    for (int off = 32; off; off >>= 1) t += __shfl_xor(t, off, 64);

    if (lane == 0) {
        float ss = 0.0f;
        #pragma unroll
        for (int q = 0; q < 4; ++q) ss += k2part[(size_t)q * NN + i];
        diff[i] = LN2 * t - LN2 * (flog2(ss) - 64.0f);
    }
}

// ---------------------------------------------------------------------------
// K6: out = mean_i diff[i]
// ---------------------------------------------------------------------------
__global__ __launch_bounds__(256) void k6_final(
    const float* __restrict__ diff, float* __restrict__ out)
{
    __shared__ float red[256];
    int tid = threadIdx.x;
    float t = 0.0f;
    for (int k = tid; k < NN; k += 256) t += diff[k];
    red[tid] = t;
    __syncthreads();
    #pragma unroll
    for (int off = 128; off; off >>= 1) {
        if (tid < off) red[tid] += red[tid + off];
        __syncthreads();
    }
    if (tid == 0) out[0] = red[0] * (1.0f / (float)NN);
}

extern "C" void kernel_launch(void* const* d_in, const int* in_sizes, int n_in,
                              void* d_out, int out_size, void* d_ws, size_t ws_size,
                              hipStream_t stream)
{
    const float* z      = (const float*)d_in[0];
    const float* z_mean = (const float*)d_in[1];
    const float* z_lv   = (const float*)d_in[2];
    float* out = (float*)d_out;

    float* ws = (float*)d_ws;
    float4* packed = (float4*)ws;                            // 2 MB
    float*  base   = ws + (size_t)NN * DD * 4;
    float2* pqT    = (float2*)base;                          // 1 MB
    float2* zz     = (float2*)(base + (size_t)NN * DD * 2);  // 1 MB
    float*  r      = base + (size_t)NN * DD * 4;             // 8 KB
    float*  sums   = r + NN;                                 // 16*N*D = 8 MB
    float*  k2part = sums + (size_t)16 * NN * DD;            // 32 KB
    float*  diff   = k2part + (size_t)4 * NN;                // 8 KB

    k1_precompute<<<NN / 64, 1024, 0, stream>>>(z, z_mean, z_lv, packed, pqT, zz, r);
    k3_perd<<<512, 512, 0, stream>>>(z, packed, sums);
    k2_logqz<<<512, 512, 0, stream>>>(zz, pqT, r, k2part);
    k5_merge<<<NN / 4, 256, 0, stream>>>(sums, k2part, diff);
    k6_final<<<1, 256, 0, stream>>>(diff, out);
}